// Round 1
// baseline (483.946 us; speedup 1.0000x reference)
//
#include <hip/hip_runtime.h>
#include <hip/hip_cooperative_groups.h>
#include <math.h>

namespace cg = cooperative_groups;

// Problem constants (from reference setup_inputs)
#define BSZ   64
#define NROWS 4096          // H*W
#define CCH   128           // channels
#define NC4   32            // channels / 4

typedef float vf4 __attribute__((ext_vector_type(4)));

__device__ __forceinline__ float dot4(float4 a, float4 b) {
    return a.x*b.x + a.y*b.y + a.z*b.z + a.w*b.w;
}

// =====================================================================
// Fused cooperative kernel: 1024 blocks x 256 threads.
// Block (b = blk>>4, sub = blk&15) owns rows [sub*256, sub*256+256) of
// batch b in ALL three phases -> x rows stay L3-hot across phases.
// __launch_bounds__(256,4): 4 waves/EU min => VGPR<=128 => 4 blocks/CU
// => 1024 blocks co-resident (cooperative launch validates this).
// =====================================================================
#define RPB 256   // rows per block

__global__ __launch_bounds__(256, 4) void k_fused(
        const float4* __restrict__ x,
        const float*  __restrict__ beta,
        const float*  __restrict__ gamma,
        float*        __restrict__ msum2,    // [1024][128] per-block channel sums
        float*        __restrict__ varpart,  // [1024] per-block h-sums
        float4*       __restrict__ out) {
    cg::grid_group grid = cg::this_grid();
    const int blk  = blockIdx.x;
    const int b    = blk >> 4;
    const int sub  = blk & 15;
    const int t    = threadIdx.x;
    const int row0 = sub * RPB;

    __shared__ float4 lds4[256];   // phase-1 partials
    __shared__ float4 mvs[32];     // normalized mean (lives phase2 -> phase3)
    __shared__ float4 bvs[32];     // beta            (lives phase2 -> phase3)
    __shared__ float  sm[128];
    __shared__ float2 red2[256];
    __shared__ float  redh[256];
    __shared__ float4 rowp[RPB];   // per-row params  (lives phase2 -> phase3)

    const float4* xb = x + ((size_t)b * NROWS + row0) * NC4;

    // ---------------- phase 1: per-block channel sums ----------------
    {
        const int c4  = t & 31;
        const int grp = t >> 5;
        float4 acc = make_float4(0.f, 0.f, 0.f, 0.f);
        for (int r = grp; r < RPB; r += 8) {
            float4 v = xb[(size_t)r * NC4 + c4];
            acc.x += v.x; acc.y += v.y; acc.z += v.z; acc.w += v.w;
        }
        lds4[t] = acc;
        __syncthreads();
        if (t < 32) {
            float4 s = lds4[t];
            #pragma unroll
            for (int k = 1; k < 8; ++k) {
                float4 v = lds4[t + 32*k];
                s.x += v.x; s.y += v.y; s.z += v.z; s.w += v.w;
            }
            ((float4*)(msum2 + (size_t)blk * CCH))[t] = make_float4(s.x, s.y, s.z, s.w);
        }
    }
    grid.sync();

    // ---------------- phase 2: mean + per-row params + var partial ----------------
    float m = 0.f, bc = 0.f;
    if (t < CCH) {
        float s = 0.f;
        #pragma unroll
        for (int k = 0; k < 16; ++k)
            s += msum2[(size_t)((b << 4) + k) * CCH + t];
        m  = s * (1.0f / (float)NROWS);
        bc = beta[t];
        sm[t] = m;
    }
    red2[t] = make_float2(m * m, bc * m);
    __syncthreads();
    #pragma unroll
    for (int s = 128; s > 0; s >>= 1) {
        if (t < s) { red2[t].x += red2[t + s].x; red2[t].y += red2[t + s].y; }
        __syncthreads();
    }
    const float smm = red2[0].x, sbm = red2[0].y;
    const float m0  = sm[0];
    const float val = fmaf(2.f * m0, m0, -smm);                 // -linner(m,m)
    const float inv = __builtin_amdgcn_rsqf(fmaxf(val, 1e-8f));
    const float mean0   = m0 * inv;
    const float inv1pm0 = __builtin_amdgcn_rcpf(1.0f + mean0);
    const float b0  = beta[0];
    const float lbm = (sbm - 2.f * b0 * m0) * inv;              // linner(beta, mean)
    if (t < CCH) {
        ((float*)mvs)[t] = sm[t] * inv;
        ((float*)bvs)[t] = bc;
    }
    __syncthreads();

    {
        const int lane = t & 63, wave = t >> 6;
        const int q    = lane >> 2;      // row-within-16
        const int ql   = lane & 3;       // chunk phase
        const int srcl = lane & ~3;      // quad base lane
        float nsum = 0.f;

        #pragma unroll
        for (int o = 0; o < 4; ++o) {
            const int lrow = o * 64 + wave * 16 + q;
            const float4* xr = xb + (size_t)lrow * NC4;

            // c = 0 peeled to capture channel 0
            float4 xv = xr[ql];
            float4 mv = mvs[ql];
            float4 bv = bvs[ql];
            float x00 = xv.x;            // valid on ql==0 lanes
            float d = dot4(xv, mv);
            float e = dot4(xv, bv);
            #pragma unroll
            for (int c = 1; c < 8; ++c) {
                int c4i = 4 * c + ql;    // quad covers 64B contiguous
                xv = xr[c4i];
                mv = mvs[c4i];
                bv = bvs[c4i];
                d = fmaf(xv.x, mv.x, fmaf(xv.y, mv.y, fmaf(xv.z, mv.z, fmaf(xv.w, mv.w, d))));
                e = fmaf(xv.x, bv.x, fmaf(xv.y, bv.y, fmaf(xv.z, bv.z, fmaf(xv.w, bv.w, e))));
            }
            d += __shfl_xor(d, 1);  e += __shfl_xor(e, 1);
            d += __shfl_xor(d, 2);  e += __shfl_xor(e, 2);
            float x0 = __shfl(x00, srcl);

            float alpha = fmaxf(fmaf(2.f * mean0, x0, -d), 1.0f + 1e-7f);
            float a2m1  = fmaxf(fmaf(alpha, alpha, -1.f), 1e-8f);   // linner(u,u)
            float sq    = sqrtf(a2m1);
            float h     = __logf(alpha + sq);                        // acosh(alpha)
            float fac   = h * __builtin_amdgcn_rcpf(sq);
            float u0    = fmaf(-alpha, mean0, x0);
            float tc    = fac * u0 * inv1pm0;
            float s_m   = fmaf(fac, alpha, tc);    // x_T = fac*x - s_m*mean - tc*e0
            float lbx   = fmaf(-2.f * b0, x0, e);  // linner(beta, x)
            float pb    = fmaf(fac, lbx, fmaf(-s_m, lbm, tc * b0)); // linner(beta, x_T)
            if (ql == 0) rowp[lrow] = make_float4(fac, alpha, tc, pb);
            nsum += 0.25f * h;           // h identical across quad; 0.25f exact
        }
        redh[t] = nsum;
    }
    __syncthreads();
    #pragma unroll
    for (int s = 128; s > 0; s >>= 1) {
        if (t < s) redh[t] += redh[t + s];
        __syncthreads();
    }
    if (t == 0) varpart[blk] = redh[0];

    grid.sync();

    // ---------------- phase 3: output (3 FMA / element) ----------------
    {
        float vsum = 0.f;
        #pragma unroll
        for (int k = 0; k < 16; ++k) vsum += varpart[(b << 4) + k];  // uniform -> s_loads
        const float scale = gamma[0] * __builtin_amdgcn_rcpf(
                                vsum * (1.0f / (float)NROWS) + 1e-5f);
        const float invb  = __builtin_amdgcn_rcpf(1.0f + b0);
        const int c4  = t & 31;
        const int grp = t >> 5;
        const float4 mv = mvs[c4];
        const float4 bv = bvs[c4];
        float4* ob = out + ((size_t)b * NROWS + row0) * NC4;

        for (int r = grp; r < RPB; r += 8) {
            float4 xv = xb[(size_t)r * NC4 + c4];
            float4 rp = rowp[r];                  // LDS broadcast within group
            float fac = rp.x, alpha = rp.y, tcv = rp.z, pb = rp.w;

            float F   = scale * fac;
            float TCv = scale * tcv;
            float SM  = fmaf(F, alpha, TCv);
            float sq  = sqrtf(fmaxf(fmaf(alpha, alpha, -1.f), 1e-8f));
            float nu  = fmaxf(scale * (fac * sq), 1e-4f);
            float PT  = scale * pb * invb;

            float ee = __expf(nu);
            float ei = __builtin_amdgcn_rcpf(ee);
            float ch = 0.5f * (ee + ei);
            float so = 0.5f * (ee - ei) * __builtin_amdgcn_rcpf(nu);

            float A = so * F;
            float B = -so * SM;
            float C = fmaf(so, PT, ch);
            float D = so * (PT - TCv);

            vf4 ov;
            ov.x = fmaf(A, xv.x, fmaf(B, mv.x, C * bv.x));
            ov.y = fmaf(A, xv.y, fmaf(B, mv.y, C * bv.y));
            ov.z = fmaf(A, xv.z, fmaf(B, mv.z, C * bv.z));
            ov.w = fmaf(A, xv.w, fmaf(B, mv.w, C * bv.w));
            if (c4 == 0) ov.x += D;
            __builtin_nontemporal_store(ov, (vf4*)&ob[(size_t)r * NC4 + c4]);
        }
    }
}

// =====================================================================
// Fallback path: the proven 3-kernel version (verbatim), used only if
// the cooperative launch is rejected (e.g. by graph capture).
// =====================================================================
#define BPB  32
#define RPBF (NROWS/BPB)

__global__ __launch_bounds__(256) void k_mean_sum(const float4* __restrict__ x,
                                                  float* __restrict__ msum) {
    int b   = blockIdx.x / BPB;
    int blk = blockIdx.x % BPB;
    int t   = threadIdx.x;
    int c4  = t & 31;
    int grp = t >> 5;
    int row0 = blk * RPBF;
    const float4* xb = x + (size_t)b * NROWS * NC4;

    float4 acc = make_float4(0.f, 0.f, 0.f, 0.f);
    for (int r = row0 + grp; r < row0 + RPBF; r += 8) {
        float4 v = xb[(size_t)r * NC4 + c4];
        acc.x += v.x; acc.y += v.y; acc.z += v.z; acc.w += v.w;
    }
    __shared__ float4 lds[256];
    lds[t] = acc;
    __syncthreads();
    if (t < 32) {
        float4 s = lds[t];
        #pragma unroll
        for (int k = 1; k < 8; ++k) {
            float4 v = lds[t + 32 * k];
            s.x += v.x; s.y += v.y; s.z += v.z; s.w += v.w;
        }
        atomicAdd(&msum[b * CCH + 4 * t + 0], s.x);
        atomicAdd(&msum[b * CCH + 4 * t + 1], s.y);
        atomicAdd(&msum[b * CCH + 4 * t + 2], s.z);
        atomicAdd(&msum[b * CCH + 4 * t + 3], s.w);
    }
}

__global__ __launch_bounds__(256) void k_rows(const float4* __restrict__ x,
                                              const float* __restrict__ msum,
                                              const float* __restrict__ beta,
                                              float* __restrict__ mean,
                                              float* __restrict__ varsum,
                                              float4* __restrict__ rowpg) {
    int blk = blockIdx.x;
    int b   = blk >> 4;
    int sub = blk & 15;
    int t   = threadIdx.x;

    __shared__ float  sm[128];
    __shared__ float4 mvs[32];
    __shared__ float4 bvs[32];
    __shared__ float2 red2[256];
    __shared__ float  redh[256];

    float m = 0.f, bc = 0.f;
    if (t < 128) {
        m  = msum[b * CCH + t] * (1.0f / (float)NROWS);
        bc = beta[t];
        sm[t] = m;
    }
    red2[t] = make_float2(m * m, bc * m);
    __syncthreads();
    #pragma unroll
    for (int s = 128; s > 0; s >>= 1) {
        if (t < s) { red2[t].x += red2[t + s].x; red2[t].y += red2[t + s].y; }
        __syncthreads();
    }
    float smm = red2[0].x, sbm = red2[0].y;
    float m0  = sm[0];
    float val = fmaf(2.f * m0, m0, -smm);
    float inv = __builtin_amdgcn_rsqf(fmaxf(val, 1e-8f));
    float mean0   = m0 * inv;
    float inv1pm0 = __builtin_amdgcn_rcpf(1.0f + mean0);
    float b0  = beta[0];
    float lbm = (sbm - 2.f * b0 * m0) * inv;
    if (t < 128) {
        float mc = sm[t] * inv;
        ((float*)mvs)[t] = mc;
        ((float*)bvs)[t] = bc;
        if (sub == 0) mean[b * CCH + t] = mc;
    }
    __syncthreads();

    int lane = t & 63, wave = t >> 6;
    int q  = lane >> 2;
    int ql = lane & 3;
    int srcl = lane & ~3;
    float nsum = 0.f;

    #pragma unroll
    for (int o = 0; o < 4; ++o) {
        int row = sub * 256 + o * 64 + wave * 16 + q;
        const float4* xr = x + ((size_t)b * NROWS + row) * NC4;

        float4 xv = xr[ql];
        float4 mv = mvs[ql];
        float4 bv = bvs[ql];
        float x00 = xv.x;
        float d = dot4(xv, mv);
        float e = dot4(xv, bv);
        #pragma unroll
        for (int c = 1; c < 8; ++c) {
            int c4 = 4 * c + ql;
            xv = xr[c4];
            mv = mvs[c4];
            bv = bvs[c4];
            d = fmaf(xv.x, mv.x, fmaf(xv.y, mv.y, fmaf(xv.z, mv.z, fmaf(xv.w, mv.w, d))));
            e = fmaf(xv.x, bv.x, fmaf(xv.y, bv.y, fmaf(xv.z, bv.z, fmaf(xv.w, bv.w, e))));
        }
        d += __shfl_xor(d, 1);  e += __shfl_xor(e, 1);
        d += __shfl_xor(d, 2);  e += __shfl_xor(e, 2);
        float x0 = __shfl(x00, srcl);

        float alpha = fmaxf(fmaf(2.f * mean0, x0, -d), 1.0f + 1e-7f);
        float a2m1  = fmaxf(fmaf(alpha, alpha, -1.f), 1e-8f);
        float sq    = sqrtf(a2m1);
        float h     = __logf(alpha + sq);
        float fac   = h * __builtin_amdgcn_rcpf(sq);
        float u0    = fmaf(-alpha, mean0, x0);
        float tc    = fac * u0 * inv1pm0;
        float s_m   = fmaf(fac, alpha, tc);
        float lbx   = fmaf(-2.f * b0, x0, e);
        float pb    = fmaf(fac, lbx, fmaf(-s_m, lbm, tc * b0));
        if (ql == 0) rowpg[(size_t)b * NROWS + row] = make_float4(fac, alpha, tc, pb);
        nsum += 0.25f * h;
    }

    redh[t] = nsum;
    __syncthreads();
    #pragma unroll
    for (int s = 128; s > 0; s >>= 1) {
        if (t < s) redh[t] += redh[t + s];
        __syncthreads();
    }
    if (t == 0) atomicAdd(&varsum[b], redh[0]);
}

__global__ __launch_bounds__(256) void k_out(const float4* __restrict__ x,
                                             const float* __restrict__ mean,
                                             const float* __restrict__ varsum,
                                             const float* __restrict__ beta,
                                             const float* __restrict__ gamma,
                                             const float4* __restrict__ rowpg,
                                             float4* __restrict__ out) {
    int b   = blockIdx.x / BPB;
    int blk = blockIdx.x % BPB;
    int t   = threadIdx.x;
    int c4  = t & 31;
    int grp = t >> 5;

    const float* meanb = mean + b * CCH;
    float4 mv = ((const float4*)meanb)[c4];
    float4 bv = ((const float4*)beta)[c4];
    float  b0 = beta[0];
    float  invb  = __builtin_amdgcn_rcpf(1.0f + b0);
    float  scale = gamma[0] * __builtin_amdgcn_rcpf(
                        varsum[b] * (1.0f / (float)NROWS) + 1e-5f);

    const float4* xb = x + (size_t)b * NROWS * NC4;
    float4*       ob = out + (size_t)b * NROWS * NC4;
    int row0 = blk * RPBF;

    for (int r = row0 + grp; r < row0 + RPBF; r += 8) {
        float4 xv = xb[(size_t)r * NC4 + c4];
        float4 rp = rowpg[(size_t)b * NROWS + r];
        float fac = rp.x, alpha = rp.y, tcv = rp.z, pb = rp.w;

        float F   = scale * fac;
        float TCv = scale * tcv;
        float SM  = fmaf(F, alpha, TCv);
        float sq  = sqrtf(fmaxf(fmaf(alpha, alpha, -1.f), 1e-8f));
        float nu  = fmaxf(scale * (fac * sq), 1e-4f);
        float PT  = scale * pb * invb;

        float ee = __expf(nu);
        float ei = __builtin_amdgcn_rcpf(ee);
        float ch = 0.5f * (ee + ei);
        float so = 0.5f * (ee - ei) * __builtin_amdgcn_rcpf(nu);

        float A = so * F;
        float B = -so * SM;
        float C = fmaf(so, PT, ch);
        float D = so * (PT - TCv);

        vf4 ov;
        ov.x = fmaf(A, xv.x, fmaf(B, mv.x, C * bv.x));
        ov.y = fmaf(A, xv.y, fmaf(B, mv.y, C * bv.y));
        ov.z = fmaf(A, xv.z, fmaf(B, mv.z, C * bv.z));
        ov.w = fmaf(A, xv.w, fmaf(B, mv.w, C * bv.w));
        if (c4 == 0) ov.x += D;
        __builtin_nontemporal_store(ov, (vf4*)&ob[(size_t)r * NC4 + c4]);
    }
}

// ---------- launch ----------
extern "C" void kernel_launch(void* const* d_in, const int* in_sizes, int n_in,
                              void* d_out, int out_size, void* d_ws, size_t ws_size,
                              hipStream_t stream) {
    const float4* x     = (const float4*)d_in[0];
    const float*  beta  = (const float*)d_in[1];
    const float*  gamma = (const float*)d_in[2];
    float4*       out   = (float4*)d_out;

    // Fused-path workspace: msum2 [1024][128] + varpart [1024]  (~516 KB)
    float* msum2   = (float*)d_ws;
    float* varpart = msum2 + 1024 * CCH;

    void* args[6] = { (void*)&x, (void*)&beta, (void*)&gamma,
                      (void*)&msum2, (void*)&varpart, (void*)&out };
    hipError_t err = hipLaunchCooperativeKernel((const void*)k_fused,
                                                dim3(1024), dim3(256),
                                                args, 0, stream);
    if (err != hipSuccess) {
        // Fallback: proven 3-kernel path (original workspace layout).
        float* ws     = (float*)d_ws;
        float* msum   = ws;                 // 8192 floats
        float* varsum = ws + 8192;          // 64
        float* mean   = ws + 8256;          // 8192
        float4* rowpg = (float4*)((char*)d_ws + 65792);

        hipMemsetAsync(ws, 0, (8192 + 64) * sizeof(float), stream);
        k_mean_sum<<<dim3(BSZ * BPB), dim3(256), 0, stream>>>(x, msum);
        k_rows<<<dim3(1024), dim3(256), 0, stream>>>(
            x, msum, beta, mean, varsum, rowpg);
        k_out<<<dim3(BSZ * BPB), dim3(256), 0, stream>>>(
            x, mean, varsum, beta, gamma, rowpg, out);
    }
}

// Round 2
// 275.545 us; speedup vs baseline: 1.7563x; 1.7563x over previous
//
#include <hip/hip_runtime.h>
#include <math.h>

// Problem constants (from reference setup_inputs)
#define BSZ   64
#define NROWS 4096          // H*W
#define CCH   128           // channels
#define NC4   32            // channels / 4

typedef float vf4 __attribute__((ext_vector_type(4)));

__device__ __forceinline__ float dot4(float4 a, float4 b) {
    return a.x*b.x + a.y*b.y + a.z*b.z + a.w*b.w;
}

// =====================================================================
// kernel 1: per-block channel partial sums -> plain stores (no atomics,
// no memset needed). 2048 blocks (32 per batch) x 256 threads.
// =====================================================================
#define BPB1 32
#define RPB1 (NROWS/BPB1)   // 128 rows per block

__global__ __launch_bounds__(256) void k_sum(const float4* __restrict__ x,
                                             float* __restrict__ part) {
    const int gb  = blockIdx.x;          // 0..2047
    const int b   = gb >> 5;
    const int blk = gb & 31;
    const int t   = threadIdx.x;
    const int c4  = t & 31;
    const int grp = t >> 5;
    const float4* xb = x + ((size_t)b * NROWS + blk * RPB1) * NC4;

    float4 acc = make_float4(0.f, 0.f, 0.f, 0.f);
    #pragma unroll 4
    for (int r = grp; r < RPB1; r += 8) {
        float4 v = xb[(size_t)r * NC4 + c4];
        acc.x += v.x; acc.y += v.y; acc.z += v.z; acc.w += v.w;
    }
    __shared__ float4 lds[256];
    lds[t] = acc;
    __syncthreads();
    if (t < 32) {
        float4 s = lds[t];
        #pragma unroll
        for (int k = 1; k < 8; ++k) {
            float4 v = lds[t + 32 * k];
            s.x += v.x; s.y += v.y; s.z += v.z; s.w += v.w;
        }
        ((float4*)(part + (size_t)gb * CCH))[t] = make_float4(s.x, s.y, s.z, s.w);
    }
}

// =====================================================================
// kernel 2: mean (from partials) + per-row params + variance partials.
// 1024 blocks (16 per batch, 256 rows each) x 256 threads.
// Verified quad-per-row scheme from the 282 us version, with the
// atomic varsum replaced by a plain per-block partial store.
// =====================================================================
__global__ __launch_bounds__(256) void k_rows(const float4* __restrict__ x,
                                              const float* __restrict__ part,
                                              const float* __restrict__ beta,
                                              float* __restrict__ mean,
                                              float* __restrict__ varpart,
                                              float4* __restrict__ rowp) {
    const int blk = blockIdx.x;          // 0..1023
    const int b   = blk >> 4;            // 16 blocks per batch
    const int sub = blk & 15;
    const int t   = threadIdx.x;

    __shared__ float  sm[128];           // raw mean m (pre-normalization)
    __shared__ float4 mvs[32];           // normalized mean
    __shared__ float4 bvs[32];           // beta
    __shared__ float2 red2[256];
    __shared__ float  redh[256];

    float m = 0.f, bc = 0.f;
    if (t < 128) {
        float s = 0.f;
        #pragma unroll
        for (int k = 0; k < 32; ++k)
            s += part[(size_t)((b << 5) + k) * CCH + t];
        m  = s * (1.0f / (float)NROWS);
        bc = beta[t];
        sm[t] = m;
    }
    red2[t] = make_float2(m * m, bc * m);
    __syncthreads();
    #pragma unroll
    for (int s = 128; s > 0; s >>= 1) {
        if (t < s) { red2[t].x += red2[t + s].x; red2[t].y += red2[t + s].y; }
        __syncthreads();
    }
    const float smm = red2[0].x, sbm = red2[0].y;
    const float m0  = sm[0];
    const float val = fmaf(2.f * m0, m0, -smm);                 // -linner(m,m)
    const float inv = __builtin_amdgcn_rsqf(fmaxf(val, 1e-8f));
    const float mean0   = m0 * inv;
    const float inv1pm0 = __builtin_amdgcn_rcpf(1.0f + mean0);
    const float b0  = beta[0];
    const float lbm = (sbm - 2.f * b0 * m0) * inv;              // linner(beta, mean)
    if (t < 128) {
        float mc = sm[t] * inv;
        ((float*)mvs)[t] = mc;
        ((float*)bvs)[t] = bc;
        if (sub == 0) mean[b * CCH + t] = mc;
    }
    __syncthreads();

    const int lane = t & 63, wave = t >> 6;
    const int q    = lane >> 2;      // row-within-16
    const int ql   = lane & 3;       // chunk phase
    const int srcl = lane & ~3;      // quad base lane
    float nsum = 0.f;

    #pragma unroll
    for (int o = 0; o < 4; ++o) {
        const int row = sub * 256 + o * 64 + wave * 16 + q;
        const float4* xr = x + ((size_t)b * NROWS + row) * NC4;

        // c = 0 peeled to capture channel 0
        float4 xv = xr[ql];
        float4 mv = mvs[ql];
        float4 bv = bvs[ql];
        float x00 = xv.x;            // valid on ql==0 lanes
        float d = dot4(xv, mv);
        float e = dot4(xv, bv);
        #pragma unroll
        for (int c = 1; c < 8; ++c) {
            int c4i = 4 * c + ql;    // quad covers 64B contiguous
            xv = xr[c4i];
            mv = mvs[c4i];
            bv = bvs[c4i];
            d = fmaf(xv.x, mv.x, fmaf(xv.y, mv.y, fmaf(xv.z, mv.z, fmaf(xv.w, mv.w, d))));
            e = fmaf(xv.x, bv.x, fmaf(xv.y, bv.y, fmaf(xv.z, bv.z, fmaf(xv.w, bv.w, e))));
        }
        d += __shfl_xor(d, 1);  e += __shfl_xor(e, 1);
        d += __shfl_xor(d, 2);  e += __shfl_xor(e, 2);
        float x0 = __shfl(x00, srcl);

        float alpha = fmaxf(fmaf(2.f * mean0, x0, -d), 1.0f + 1e-7f);
        float a2m1  = fmaxf(fmaf(alpha, alpha, -1.f), 1e-8f);   // linner(u,u) = a^2-1
        float sq    = sqrtf(a2m1);
        float h     = __logf(alpha + sq);                        // acosh(alpha)
        float fac   = h * __builtin_amdgcn_rcpf(sq);
        float u0    = fmaf(-alpha, mean0, x0);
        float tc    = fac * u0 * inv1pm0;
        float s_m   = fmaf(fac, alpha, tc);    // x_T = fac*x - s_m*mean - tc*e0
        float lbx   = fmaf(-2.f * b0, x0, e);  // linner(beta, x)
        float pb    = fmaf(fac, lbx, fmaf(-s_m, lbm, tc * b0)); // linner(beta, x_T)
        if (ql == 0) rowp[(size_t)b * NROWS + row] = make_float4(fac, alpha, tc, pb);
        nsum += 0.25f * h;           // h identical across quad; 0.25f exact
    }

    redh[t] = nsum;
    __syncthreads();
    #pragma unroll
    for (int s = 128; s > 0; s >>= 1) {
        if (t < s) redh[t] += redh[t + s];
        __syncthreads();
    }
    if (t == 0) varpart[blk] = redh[0];   // plain store, no atomic
}

// =====================================================================
// kernel 3: reduction-free output, 3 FMA / element.
// 2048 blocks (32 per batch) x 256 threads.
// =====================================================================
#define BPB3 32
#define RPB3 (NROWS/BPB3)   // 128

__global__ __launch_bounds__(256) void k_out(const float4* __restrict__ x,
                                             const float* __restrict__ mean,
                                             const float* __restrict__ varpart,
                                             const float* __restrict__ beta,
                                             const float* __restrict__ gamma,
                                             const float4* __restrict__ rowp,
                                             float4* __restrict__ out) {
    const int b   = blockIdx.x / BPB3;
    const int blk = blockIdx.x % BPB3;
    const int t   = threadIdx.x;
    const int c4  = t & 31;
    const int grp = t >> 5;

    const float* meanb = mean + b * CCH;
    float4 mv = ((const float4*)meanb)[c4];
    float4 bv = ((const float4*)beta)[c4];
    float  b0 = beta[0];
    float  invb = __builtin_amdgcn_rcpf(1.0f + b0);

    float vsum = 0.f;
    #pragma unroll
    for (int k = 0; k < 16; ++k) vsum += varpart[(b << 4) + k];  // uniform
    float scale = gamma[0] * __builtin_amdgcn_rcpf(
                      vsum * (1.0f / (float)NROWS) + 1e-5f);

    const float4* xb = x + (size_t)b * NROWS * NC4;
    float4*       ob = out + (size_t)b * NROWS * NC4;
    const int row0 = blk * RPB3;

    #pragma unroll 4
    for (int r = row0 + grp; r < row0 + RPB3; r += 8) {
        float4 xv = xb[(size_t)r * NC4 + c4];
        float4 rp = rowp[(size_t)b * NROWS + r];   // broadcast within group
        float fac = rp.x, alpha = rp.y, tcv = rp.z, pb = rp.w;

        float F   = scale * fac;
        float TCv = scale * tcv;
        float SM  = fmaf(F, alpha, TCv);
        float sq  = sqrtf(fmaxf(fmaf(alpha, alpha, -1.f), 1e-8f));
        float nu  = fmaxf(scale * (fac * sq), 1e-4f);  // = sqrt(clip(linner,1e-8))
        float PT  = scale * pb * invb;

        float ee = __expf(nu);
        float ei = __builtin_amdgcn_rcpf(ee);
        float ch = 0.5f * (ee + ei);
        float so = 0.5f * (ee - ei) * __builtin_amdgcn_rcpf(nu);

        float A = so * F;
        float B = -so * SM;
        float C = fmaf(so, PT, ch);
        float D = so * (PT - TCv);

        vf4 ov;
        ov.x = fmaf(A, xv.x, fmaf(B, mv.x, C * bv.x));
        ov.y = fmaf(A, xv.y, fmaf(B, mv.y, C * bv.y));
        ov.z = fmaf(A, xv.z, fmaf(B, mv.z, C * bv.z));
        ov.w = fmaf(A, xv.w, fmaf(B, mv.w, C * bv.w));
        if (c4 == 0) ov.x += D;
        // non-temporal full-line store: don't evict x from L3
        __builtin_nontemporal_store(ov, (vf4*)&ob[(size_t)r * NC4 + c4]);
    }
}

// ---------- launch ----------
extern "C" void kernel_launch(void* const* d_in, const int* in_sizes, int n_in,
                              void* d_out, int out_size, void* d_ws, size_t ws_size,
                              hipStream_t stream) {
    const float4* x     = (const float4*)d_in[0];
    const float*  beta  = (const float*)d_in[1];
    const float*  gamma = (const float*)d_in[2];
    float4*       out   = (float4*)d_out;

    // Workspace layout (all plain-stored, no memset required):
    //   part    [2048][128] floats : 1 MB     @ 0
    //   varpart [1024] floats      : 4 KB     @ 1 MB
    //   mean    [64][128] floats   : 32 KB    @ 1 MB + 4 KB
    //   rowp    [64*4096] float4   : 4 MB     @ 2 MB (16B aligned)
    char* wsb = (char*)d_ws;
    float*  part    = (float*)(wsb);
    float*  varpart = (float*)(wsb + (1 << 20));
    float*  mean    = (float*)(wsb + (1 << 20) + 4096);
    float4* rowp    = (float4*)(wsb + (2 << 20));

    k_sum<<<dim3(BSZ * BPB1), dim3(256), 0, stream>>>(x, part);
    k_rows<<<dim3(1024), dim3(256), 0, stream>>>(
        x, part, beta, mean, varpart, rowp);
    k_out<<<dim3(BSZ * BPB3), dim3(256), 0, stream>>>(
        x, mean, varpart, beta, gamma, rowp, out);
}